// Round 1
// baseline (226.026 us; speedup 1.0000x reference)
//
#include <hip/hip_runtime.h>

// BinaryLinearLayer: C = (sign(X) @ sign(W)) * (relu(alpha)*outer(relu(betta),relu(gamma))).flatten()
// M=8192, K=4096, N=2048.
// Strategy: binarize to bf16 (+/-1, 0 exact) -> bf16 MFMA GEMM (exact integer dots in f32 acc).

#define M_DIM 8192
#define K_DIM 4096
#define N_DIM 2048

typedef short short8 __attribute__((ext_vector_type(8)));
typedef unsigned short ushort8 __attribute__((ext_vector_type(8)));
typedef float f32x4 __attribute__((ext_vector_type(4)));

__device__ __forceinline__ unsigned short sign_bf16(float x) {
  // sign(x) in bf16 bits: +1 -> 0x3F80, -1 -> 0xBF80, 0 -> 0x0000 (handles +/-0)
  if (x == 0.0f) return 0;
  return (unsigned short)(0x3F80u | ((__float_as_uint(x) >> 16) & 0x8000u));
}

__device__ __forceinline__ void gload_lds16(const void* g, void* lds) {
  // async global->LDS, 16B per lane; LDS dest = wave-uniform base + lane*16
  __builtin_amdgcn_global_load_lds(
      (const __attribute__((address_space(1))) unsigned int*)g,
      (__attribute__((address_space(3))) unsigned int*)lds, 16, 0, 0);
}

// ---------------- binarize X: f32 [M][K] -> bf16-bits [M][K] ----------------
__global__ void binX_kernel(const float* __restrict__ X,
                            unsigned short* __restrict__ Xb, int n8) {
  int stride = gridDim.x * blockDim.x;
  for (int i = blockIdx.x * blockDim.x + threadIdx.x; i < n8; i += stride) {
    int idx = i * 8;
    float4 v0 = *(const float4*)&X[idx];
    float4 v1 = *(const float4*)&X[idx + 4];
    ushort8 r;
    r[0] = sign_bf16(v0.x); r[1] = sign_bf16(v0.y);
    r[2] = sign_bf16(v0.z); r[3] = sign_bf16(v0.w);
    r[4] = sign_bf16(v1.x); r[5] = sign_bf16(v1.y);
    r[6] = sign_bf16(v1.z); r[7] = sign_bf16(v1.w);
    *(ushort8*)&Xb[idx] = r;
  }
}

// ------------- binarize + transpose W: f32 [K][N] -> bf16-bits Wt [N][K] ----
__global__ void binWt_kernel(const float* __restrict__ W,
                             unsigned short* __restrict__ Wt) {
  __shared__ float tile[32][33];
  const int n0 = blockIdx.x * 32;
  const int k0 = blockIdx.y * 32;
  const int t = threadIdx.x;
  const int tc = t & 31;   // 0..31
  const int tr = t >> 5;   // 0..7
#pragma unroll
  for (int i = 0; i < 32; i += 8)
    tile[tr + i][tc] = W[(size_t)(k0 + tr + i) * N_DIM + n0 + tc];
  __syncthreads();
#pragma unroll
  for (int i = 0; i < 32; i += 8) {
    float x = tile[tc][tr + i];
    Wt[(size_t)(n0 + tr + i) * K_DIM + k0 + tc] = sign_bf16(x);
  }
}

// ---------------- GEMM: C[M][N] = A[M][K] * Wt[N][K]^T, scaled --------------
// 128x128 tile, BK=64, 256 threads = 4 waves (2x2), each wave 64x64 out,
// 4x4 fragments of mfma_f32_16x16x32_bf16. global_load_lds width-16 staging.
__global__ __launch_bounds__(256) void gemm_bin_kernel(
    const unsigned short* __restrict__ A,   // [M][K] bf16 bits
    const unsigned short* __restrict__ Bt,  // [N][K] bf16 bits
    const float* __restrict__ alpha,
    const float* __restrict__ betta,
    const float* __restrict__ gamma,
    float* __restrict__ C) {
  __shared__ unsigned short sA[128 * 64];
  __shared__ unsigned short sB[128 * 64];

  const int t = threadIdx.x;
  const int lane = t & 63;
  const int w = t >> 6;
  const int wr = w >> 1, wc = w & 1;

  const int bid = blockIdx.x;
  const int bm = bid >> 4;   // 64 row-blocks (consecutive bids share A panel for L2)
  const int bn = bid & 15;   // 16 col-blocks
  const int row0 = bm * 128;
  const int col0 = bn * 128;

  f32x4 acc[4][4];
#pragma unroll
  for (int m = 0; m < 4; ++m)
#pragma unroll
    for (int n = 0; n < 4; ++n) acc[m][n] = {0.f, 0.f, 0.f, 0.f};

  for (int kt = 0; kt < K_DIM; kt += 64) {
    // stage A,B tiles: each 128 rows x 64 k x 2B = 16 KB = 1024 x 16B chunks
#pragma unroll
    for (int j = 0; j < 4; ++j) {
      int c = j * 256 + t;       // chunk id; lane-contiguous within wave
      int r = c >> 3;            // tile row
      int k8 = (c & 7) * 8;      // k element offset
      gload_lds16(&A[(size_t)(row0 + r) * K_DIM + kt + k8], &sA[c * 8]);
      gload_lds16(&Bt[(size_t)(col0 + r) * K_DIM + kt + k8], &sB[c * 8]);
    }
    __syncthreads();   // drains vmcnt before barrier (compiler-inserted)

#pragma unroll
    for (int kk = 0; kk < 2; ++kk) {
      const int kb = kk * 32 + (lane >> 4) * 8;
      short8 a[4], b[4];
#pragma unroll
      for (int m = 0; m < 4; ++m)
        a[m] = *(const short8*)&sA[(wr * 64 + m * 16 + (lane & 15)) * 64 + kb];
#pragma unroll
      for (int n = 0; n < 4; ++n)
        b[n] = *(const short8*)&sB[(wc * 64 + n * 16 + (lane & 15)) * 64 + kb];
#pragma unroll
      for (int m = 0; m < 4; ++m)
#pragma unroll
        for (int n = 0; n < 4; ++n)
          acc[m][n] = __builtin_amdgcn_mfma_f32_16x16x32_bf16(a[m], b[n], acc[m][n], 0, 0, 0);
    }
    __syncthreads();
  }

  // epilogue: scale[col] = relu(alpha)*relu(betta[col/64])*relu(gamma[col%64])
  const float ra = fmaxf(alpha[0], 0.0f);
#pragma unroll
  for (int n = 0; n < 4; ++n) {
    const int col = col0 + wc * 64 + n * 16 + (lane & 15);
    const float sc = ra * fmaxf(betta[col >> 6], 0.0f) * fmaxf(gamma[col & 63], 0.0f);
#pragma unroll
    for (int m = 0; m < 4; ++m) {
      const int row = row0 + wr * 64 + m * 16 + (lane >> 4) * 4;
#pragma unroll
      for (int r = 0; r < 4; ++r)
        C[(size_t)(row + r) * N_DIM + col] = acc[m][n][r] * sc;
    }
  }
}

extern "C" void kernel_launch(void* const* d_in, const int* in_sizes, int n_in,
                              void* d_out, int out_size, void* d_ws, size_t ws_size,
                              hipStream_t stream) {
  const float* X = (const float*)d_in[0];      // [8192][4096]
  const float* W = (const float*)d_in[1];      // [4096][2048]
  const float* alpha = (const float*)d_in[2];  // [1]
  const float* betta = (const float*)d_in[3];  // [32]
  const float* gamma = (const float*)d_in[4];  // [64]
  float* out = (float*)d_out;                  // [8192][2048]

  // workspace: Xb (64 MiB) + Wt (16 MiB)
  unsigned short* Xb = (unsigned short*)d_ws;
  unsigned short* Wt = (unsigned short*)((char*)d_ws + (size_t)M_DIM * K_DIM * 2);

  binX_kernel<<<4096, 256, 0, stream>>>(X, Xb, (M_DIM * K_DIM) / 8);
  binWt_kernel<<<dim3(N_DIM / 32, K_DIM / 32), 256, 0, stream>>>(W, Wt);
  gemm_bin_kernel<<<(M_DIM / 128) * (N_DIM / 128), 256, 0, stream>>>(
      Xb, Wt, alpha, betta, gamma, out);
}

// Round 2
// 79.996 us; speedup vs baseline: 2.8255x; 2.8255x over previous
//
#include <hip/hip_runtime.h>

// BinaryLinearLayer: C = (sign(X) @ sign(W)) * (relu(alpha)*outer(relu(betta),relu(gamma))).flatten()
// M=8192, K=4096, N=2048.
// Strategy: binarize to MX-fp4 (e2m1: +/-1, 0 exact; unit E8M0 scales) ->
// mfma_scale_f32_32x32x64_f8f6f4 GEMM (exact integer dots in f32 acc).
// Note: +/-1 dots are invariant under k-permutation, so fp4 nibble/k-order
// inside the fragment cannot affect correctness (A and B share the HW k-map).

#define M_DIM 8192
#define K_DIM 4096
#define N_DIM 2048
#define KB    (K_DIM / 2)   // bytes per packed row = 2048

typedef int i32x4 __attribute__((ext_vector_type(4)));
typedef int i32x8 __attribute__((ext_vector_type(8)));
typedef float f32x16 __attribute__((ext_vector_type(16)));

__device__ __forceinline__ unsigned int nib4(float x) {
  // sign(x) as fp4 e2m1 nibble: +1 -> 0x2, -1 -> 0xA, 0 -> 0x0
  unsigned int s = (__float_as_uint(x) >> 28) & 0x8u;
  return x == 0.0f ? 0u : (0x2u | s);
}

__device__ __forceinline__ void gload_lds16(const void* g, void* lds) {
  __builtin_amdgcn_global_load_lds(
      (const __attribute__((address_space(1))) unsigned int*)g,
      (__attribute__((address_space(3))) unsigned int*)lds, 16, 0, 0);
}

// ---------------- binarize X: f32 [M][K] -> fp4 nibbles [M][K/2 bytes] -----
__global__ void binX4_kernel(const float* __restrict__ X,
                             unsigned int* __restrict__ Xq, int n16) {
  int stride = gridDim.x * blockDim.x;
  for (int i = blockIdx.x * blockDim.x + threadIdx.x; i < n16; i += stride) {
    size_t base = (size_t)i * 16;
    unsigned int lo = 0, hi = 0;
#pragma unroll
    for (int j = 0; j < 2; ++j) {
      float4 v0 = *(const float4*)&X[base + j * 8];
      float4 v1 = *(const float4*)&X[base + j * 8 + 4];
      unsigned int p = 0;
      p |= nib4(v0.x) << 0;  p |= nib4(v0.y) << 4;
      p |= nib4(v0.z) << 8;  p |= nib4(v0.w) << 12;
      p |= nib4(v1.x) << 16; p |= nib4(v1.y) << 20;
      p |= nib4(v1.z) << 24; p |= nib4(v1.w) << 28;
      if (j == 0) lo = p; else hi = p;
    }
    uint2 r; r.x = lo; r.y = hi;
    *(uint2*)&Xq[(size_t)i * 2] = r;
  }
}

// ------- binarize + transpose W: f32 [K][N] -> fp4 Wq [N][K/2 bytes] -------
__global__ void binW4_kernel(const float* __restrict__ W,
                             unsigned short* __restrict__ Wq) {
  __shared__ float tile[32][33];
  const int n0 = blockIdx.x * 32;
  const int k0 = blockIdx.y * 32;
  const int t = threadIdx.x;
  const int tc = t & 31;
  const int tr = t >> 5;
#pragma unroll
  for (int i = 0; i < 32; i += 8)
    tile[tr + i][tc] = W[(size_t)(k0 + tr + i) * N_DIM + n0 + tc];
  __syncthreads();
  const int r = t >> 3;   // 0..31 (n-local)
  const int c = t & 7;    // 0..7  (k-chunk of 4)
  unsigned int b0 = nib4(tile[c * 4 + 0][r]) | (nib4(tile[c * 4 + 1][r]) << 4);
  unsigned int b1 = nib4(tile[c * 4 + 2][r]) | (nib4(tile[c * 4 + 3][r]) << 4);
  Wq[(size_t)(n0 + r) * (KB / 2) + (k0 >> 2) + c] = (unsigned short)(b0 | (b1 << 8));
}

// ---------------- GEMM: C[M][N] = Xq * Wq^T (fp4 MX, unit scales) ----------
// 128x128 tile, BK=256 k (128 B/row), 4 waves (2x2), each wave 64x64 out =
// 2x2 frags of 32x32x64. XOR-swizzled LDS (granule g ^= row&7), staged via
// global_load_lds with inverse-swizzled SOURCE (linear LDS dest).
__global__ __launch_bounds__(256) void gemm_fp4_kernel(
    const unsigned char* __restrict__ Aq,   // [M][KB]
    const unsigned char* __restrict__ Bq,   // [N][KB]
    const float* __restrict__ alpha,
    const float* __restrict__ betta,
    const float* __restrict__ gamma,
    float* __restrict__ C) {
  __shared__ __align__(16) unsigned char sA[128 * 128];
  __shared__ __align__(16) unsigned char sB[128 * 128];

  const int t = threadIdx.x;
  const int lane = t & 63;
  const int l31 = lane & 31;
  const int lhi = lane >> 5;
  const int w = t >> 6;
  const int wr = w >> 1, wc = w & 1;

  const int bid = blockIdx.x;
  const int bm = bid >> 4;   // 64 row-blocks
  const int bn = bid & 15;   // 16 col-blocks
  const int row0 = bm * 128;
  const int col0 = bn * 128;

  f32x16 acc[2][2];
#pragma unroll
  for (int m = 0; m < 2; ++m)
#pragma unroll
    for (int n = 0; n < 2; ++n)
#pragma unroll
      for (int r = 0; r < 16; ++r) acc[m][n][r] = 0.f;

  for (int ktb = 0; ktb < KB; ktb += 128) {   // 128 bytes = 256 k per step
    // stage: 128 rows x 8 granules(16B) each for A and B = 1024 chunks each
#pragma unroll
    for (int j = 0; j < 4; ++j) {
      int c = j * 256 + t;
      int r = c >> 3;                       // tile row
      int gg = (c & 7) ^ (r & 7);           // inverse-swizzled source granule
      gload_lds16(&Aq[(size_t)(row0 + r) * KB + ktb + gg * 16], &sA[c * 16]);
      gload_lds16(&Bq[(size_t)(col0 + r) * KB + ktb + gg * 16], &sB[c * 16]);
    }
    __syncthreads();

#pragma unroll
    for (int kk = 0; kk < 4; ++kk) {        // 4 x k=64
      const int g = kk * 2 + lhi;
      i32x8 av[2], bv[2];
#pragma unroll
      for (int fm = 0; fm < 2; ++fm) {
        const int rr = wr * 64 + fm * 32 + l31;
        i32x4 v = *(const i32x4*)&sA[rr * 128 + ((g ^ (rr & 7)) * 16)];
        av[fm][0] = v[0]; av[fm][1] = v[1]; av[fm][2] = v[2]; av[fm][3] = v[3];
        av[fm][4] = 0; av[fm][5] = 0; av[fm][6] = 0; av[fm][7] = 0;
      }
#pragma unroll
      for (int fn = 0; fn < 2; ++fn) {
        const int rr = wc * 64 + fn * 32 + l31;
        i32x4 v = *(const i32x4*)&sB[rr * 128 + ((g ^ (rr & 7)) * 16)];
        bv[fn][0] = v[0]; bv[fn][1] = v[1]; bv[fn][2] = v[2]; bv[fn][3] = v[3];
        bv[fn][4] = 0; bv[fn][5] = 0; bv[fn][6] = 0; bv[fn][7] = 0;
      }
#pragma unroll
      for (int fm = 0; fm < 2; ++fm)
#pragma unroll
        for (int fn = 0; fn < 2; ++fn)
          acc[fm][fn] = __builtin_amdgcn_mfma_scale_f32_32x32x64_f8f6f4(
              av[fm], bv[fn], acc[fm][fn], 4, 4,   // cbsz=fp4, blgp=fp4
              0, 0x7F7F7F7F, 0, 0x7F7F7F7F);       // unit E8M0 scales
    }
    __syncthreads();
  }

  // epilogue: scale[col] = relu(alpha)*relu(betta[col/64])*relu(gamma[col%64])
  const float ra = fmaxf(alpha[0], 0.0f);
#pragma unroll
  for (int fn = 0; fn < 2; ++fn) {
    const int col = col0 + wc * 64 + fn * 32 + l31;
    const float sc = ra * fmaxf(betta[col >> 6], 0.0f) * fmaxf(gamma[col & 63], 0.0f);
#pragma unroll
    for (int fm = 0; fm < 2; ++fm) {
      const int rbase = row0 + wr * 64 + fm * 32 + 4 * lhi;
#pragma unroll
      for (int r = 0; r < 16; ++r) {
        const int row = rbase + (r & 3) + 8 * (r >> 2);
        C[(size_t)row * N_DIM + col] = acc[fm][fn][r] * sc;
      }
    }
  }
}

extern "C" void kernel_launch(void* const* d_in, const int* in_sizes, int n_in,
                              void* d_out, int out_size, void* d_ws, size_t ws_size,
                              hipStream_t stream) {
  const float* X = (const float*)d_in[0];      // [8192][4096]
  const float* W = (const float*)d_in[1];      // [4096][2048]
  const float* alpha = (const float*)d_in[2];  // [1]
  const float* betta = (const float*)d_in[3];  // [32]
  const float* gamma = (const float*)d_in[4];  // [64]
  float* out = (float*)d_out;                  // [8192][2048]

  // workspace: Xq (16 MiB) + Wq (4 MiB)
  unsigned char* Xq = (unsigned char*)d_ws;
  unsigned char* Wq = Xq + (size_t)M_DIM * KB;

  binX4_kernel<<<2048, 256, 0, stream>>>(X, (unsigned int*)Xq,
                                         (M_DIM * K_DIM) / 16);
  binW4_kernel<<<dim3(N_DIM / 32, K_DIM / 32), 256, 0, stream>>>(
      W, (unsigned short*)Wq);
  gemm_fp4_kernel<<<(M_DIM / 128) * (N_DIM / 128), 256, 0, stream>>>(
      Xq, Wq, alpha, betta, gamma, out);
}

// Round 3
// 75.508 us; speedup vs baseline: 2.9934x; 1.0594x over previous
//
#include <hip/hip_runtime.h>

// BinaryLinearLayer: C = (sign(X) @ sign(W)) * (relu(alpha)*outer(relu(betta),relu(gamma))).flatten()
// M=8192, K=4096, N=2048.
// fp4 e2m1 (+/-1, 0 exact; unit E8M0 scales) -> mfma_scale_f32_32x32x64_f8f6f4.
// GEMM: 256x256 tile, BK=256 (128B rows), 8 waves, dbuf LDS 128KB, 4-phase
// schedule per K-tile (barrier-paired phases, setprio MFMA clusters, early
// stage-issue + tile-boundary vmcnt drain), granule-XOR LDS swizzle both sides.

#define M_DIM 8192
#define K_DIM 4096
#define N_DIM 2048
#define KB    (K_DIM / 2)    // packed bytes per row = 2048
#define NT    (K_DIM / 256)  // 16 K-tiles (256 k-elems = 128 B each)

typedef int i32x4 __attribute__((ext_vector_type(4)));
typedef int i32x8 __attribute__((ext_vector_type(8)));
typedef float f32x16 __attribute__((ext_vector_type(16)));

__device__ __forceinline__ unsigned int nib4(float x) {
  // sign(x) as fp4 e2m1 nibble: +1 -> 0x2, -1 -> 0xA, 0 -> 0x0
  unsigned int s = (__float_as_uint(x) >> 28) & 0x8u;
  return x == 0.0f ? 0u : (0x2u | s);
}

__device__ __forceinline__ void gload_lds16(const void* g, void* lds) {
  __builtin_amdgcn_global_load_lds(
      (const __attribute__((address_space(1))) unsigned int*)g,
      (__attribute__((address_space(3))) unsigned int*)lds, 16, 0, 0);
}

__device__ __forceinline__ i32x8 pad8(i32x4 v) {
  i32x8 r;
  r[0] = v[0]; r[1] = v[1]; r[2] = v[2]; r[3] = v[3];
  r[4] = 0; r[5] = 0; r[6] = 0; r[7] = 0;
  return r;
}

// ---------------- binarize X: f32 [M][K] -> fp4 nibbles [M][K/2 bytes] -----
__global__ void binX4_kernel(const float* __restrict__ X,
                             unsigned int* __restrict__ Xq, int n16) {
  int stride = gridDim.x * blockDim.x;
  for (int i = blockIdx.x * blockDim.x + threadIdx.x; i < n16; i += stride) {
    size_t base = (size_t)i * 16;
    unsigned int lo = 0, hi = 0;
#pragma unroll
    for (int j = 0; j < 2; ++j) {
      float4 v0 = *(const float4*)&X[base + j * 8];
      float4 v1 = *(const float4*)&X[base + j * 8 + 4];
      unsigned int p = 0;
      p |= nib4(v0.x) << 0;  p |= nib4(v0.y) << 4;
      p |= nib4(v0.z) << 8;  p |= nib4(v0.w) << 12;
      p |= nib4(v1.x) << 16; p |= nib4(v1.y) << 20;
      p |= nib4(v1.z) << 24; p |= nib4(v1.w) << 28;
      if (j == 0) lo = p; else hi = p;
    }
    uint2 r; r.x = lo; r.y = hi;
    *(uint2*)&Xq[(size_t)i * 2] = r;
  }
}

// ------- binarize + transpose W: f32 [K][N] -> fp4 Wq [N][K/2 bytes] -------
__global__ void binW4_kernel(const float* __restrict__ W,
                             unsigned short* __restrict__ Wq) {
  __shared__ float tile[32][33];
  const int n0 = blockIdx.x * 32;
  const int k0 = blockIdx.y * 32;
  const int t = threadIdx.x;
  const int tc = t & 31;
  const int tr = t >> 5;
#pragma unroll
  for (int i = 0; i < 32; i += 8)
    tile[tr + i][tc] = W[(size_t)(k0 + tr + i) * N_DIM + n0 + tc];
  __syncthreads();
  const int r = t >> 3;
  const int c = t & 7;
  unsigned int b0 = nib4(tile[c * 4 + 0][r]) | (nib4(tile[c * 4 + 1][r]) << 4);
  unsigned int b1 = nib4(tile[c * 4 + 2][r]) | (nib4(tile[c * 4 + 3][r]) << 4);
  Wq[(size_t)(n0 + r) * (KB / 2) + (k0 >> 2) + c] = (unsigned short)(b0 | (b1 << 8));
}

// stage one 256-row x 128-B tile into LDS: 4 gload_lds16 per thread.
// LDS chunk c -> row r=c>>3, slot s=c&7 holds source granule s^(r&7)
// (inverse-swizzled source, linear LDS dest; read side applies same XOR).
__device__ __forceinline__ void stage_tile(const unsigned char* __restrict__ src,
                                           unsigned char* lds, int t) {
#pragma unroll
  for (int p = 0; p < 4; ++p) {
    int c = p * 512 + t;
    int r = c >> 3;
    int gg = (c & 7) ^ (r & 7);
    gload_lds16(src + (size_t)r * KB + gg * 16, lds + c * 16);
  }
}

// ---------------- GEMM: C[M][N] = Xq * Wq^T (fp4 MX, unit scales) ----------
__global__ __launch_bounds__(512, 2) void gemm_fp4_kernel(
    const unsigned char* __restrict__ Aq,   // [M][KB]
    const unsigned char* __restrict__ Bq,   // [N][KB]
    const float* __restrict__ alpha,
    const float* __restrict__ betta,
    const float* __restrict__ gamma,
    float* __restrict__ C) {
  __shared__ __align__(16) unsigned char smem[131072];  // 2 x (sA 32KB + sB 32KB)

  const int t = threadIdx.x;
  const int lane = t & 63;
  const int l31 = lane & 31;
  const int lhi = lane >> 5;
  const int w = t >> 6;          // 0..7
  const int wr = w >> 2;         // 0..1  (128-row half)
  const int wc = w & 3;          // 0..3  (64-col quarter)

  // bijective XCD swizzle: 256 blocks, 8 XCDs -> each XCD owns one bn panel
  const int bid = blockIdx.x;
  const int swz = (bid & 7) * 32 + (bid >> 3);
  const int bn = swz >> 5;       // 0..7
  const int bm = swz & 31;       // 0..31
  const int row0 = bm * 256;
  const int col0 = bn * 256;

  const unsigned char* Asrc = Aq + (size_t)row0 * KB;
  const unsigned char* Bsrc = Bq + (size_t)col0 * KB;

  f32x16 acc[4][2];
#pragma unroll
  for (int fm = 0; fm < 4; ++fm)
#pragma unroll
    for (int fn = 0; fn < 2; ++fn)
#pragma unroll
      for (int r = 0; r < 16; ++r) acc[fm][fn][r] = 0.f;

  // prologue: stage K-tile 0 into buf0, drain, barrier
  stage_tile(Asrc, &smem[0], t);
  stage_tile(Bsrc, &smem[32768], t);
  asm volatile("s_waitcnt vmcnt(0)" ::: "memory");
  __builtin_amdgcn_s_barrier();

  for (int kt = 0; kt < NT; ++kt) {
    const int cur = kt & 1;
    const unsigned char* pA = &smem[cur * 65536];
    const unsigned char* pB = pA + 32768;
    const int nktb = (kt + 1) * 128;

#pragma unroll
    for (int kk = 0; kk < 4; ++kk) {
      // ds-read the 6 fragments for this k-sub-iter
      const int g = kk * 2 + lhi;
      i32x4 a4[4], b4[2];
#pragma unroll
      for (int fm = 0; fm < 4; ++fm) {
        const int rr = wr * 128 + fm * 32 + l31;
        a4[fm] = *(const i32x4*)&pA[rr * 128 + ((g ^ (rr & 7)) * 16)];
      }
#pragma unroll
      for (int fn = 0; fn < 2; ++fn) {
        const int rr = wc * 64 + fn * 32 + l31;
        b4[fn] = *(const i32x4*)&pB[rr * 128 + ((g ^ (rr & 7)) * 16)];
      }
      // early stage-issue for next tile (A in phase 0, B in phase 1) so the
      // tile-end vmcnt(0) has ~2 phases of MFMA cover
      if (kk == 0 && kt + 1 < NT)
        stage_tile(Asrc + nktb, &smem[(cur ^ 1) * 65536], t);
      if (kk == 1 && kt + 1 < NT)
        stage_tile(Bsrc + nktb, &smem[(cur ^ 1) * 65536 + 32768], t);

      __builtin_amdgcn_s_barrier();
      asm volatile("s_waitcnt lgkmcnt(0)" ::: "memory");
      __builtin_amdgcn_sched_barrier(0);
      __builtin_amdgcn_s_setprio(1);
#pragma unroll
      for (int fm = 0; fm < 4; ++fm) {
        i32x8 av = pad8(a4[fm]);
#pragma unroll
        for (int fn = 0; fn < 2; ++fn)
          acc[fm][fn] = __builtin_amdgcn_mfma_scale_f32_32x32x64_f8f6f4(
              av, pad8(b4[fn]), acc[fm][fn], 4, 4,   // cbsz=fp4, blgp=fp4
              0, 0x7F7F7F7F, 0, 0x7F7F7F7F);         // unit E8M0 scales
      }
      __builtin_amdgcn_s_setprio(0);
      if (kk < 3) __builtin_amdgcn_s_barrier();
    }
    // tile boundary: all stage loads for kt+1 must have landed (all waves)
    asm volatile("s_waitcnt vmcnt(0)" ::: "memory");
    __builtin_amdgcn_s_barrier();
  }

  // epilogue: scale[col] = relu(alpha)*relu(betta[col/64])*relu(gamma[col%64])
  const float ra = fmaxf(alpha[0], 0.0f);
#pragma unroll
  for (int fn = 0; fn < 2; ++fn) {
    const int col = col0 + wc * 64 + fn * 32 + l31;
    const float sc = ra * fmaxf(betta[col >> 6], 0.0f) * fmaxf(gamma[col & 63], 0.0f);
#pragma unroll
    for (int fm = 0; fm < 4; ++fm) {
      const int rbase = row0 + wr * 128 + fm * 32 + 4 * lhi;
#pragma unroll
      for (int r = 0; r < 16; ++r) {
        const int row = rbase + (r & 3) + 8 * (r >> 2);
        C[(size_t)row * N_DIM + col] = acc[fm][fn][r] * sc;
      }
    }
  }
}

extern "C" void kernel_launch(void* const* d_in, const int* in_sizes, int n_in,
                              void* d_out, int out_size, void* d_ws, size_t ws_size,
                              hipStream_t stream) {
  const float* X = (const float*)d_in[0];      // [8192][4096]
  const float* W = (const float*)d_in[1];      // [4096][2048]
  const float* alpha = (const float*)d_in[2];  // [1]
  const float* betta = (const float*)d_in[3];  // [32]
  const float* gamma = (const float*)d_in[4];  // [64]
  float* out = (float*)d_out;                  // [8192][2048]

  unsigned char* Xq = (unsigned char*)d_ws;            // 16 MiB
  unsigned char* Wq = Xq + (size_t)M_DIM * KB;         // 4 MiB

  binX4_kernel<<<2048, 256, 0, stream>>>(X, (unsigned int*)Xq,
                                         (M_DIM * K_DIM) / 16);
  binW4_kernel<<<dim3(N_DIM / 32, K_DIM / 32), 256, 0, stream>>>(
      W, (unsigned short*)Wq);
  gemm_fp4_kernel<<<(M_DIM / 256) * (N_DIM / 256), 512, 0, stream>>>(
      Xq, Wq, alpha, betta, gamma, out);
}